// Round 6
// baseline (126.905 us; speedup 1.0000x reference)
//
#include <hip/hip_runtime.h>
#include <hip/hip_bf16.h>

#define N_GAUSS 4096
#define H 512
#define W 512
#define HW (H * W)

// ---------------- workspace layout (floats) ----------------
// cx      [4096]  @ 0
// cy      [4096]  @ 4096
// dz      [4096]  @ 8192
// key     [4096]  @ 12288
// rank    [4096]  @ 16384     (int, zeroed by proj_kernel)
// sorted  [4096*8]@ 20480     (AoS: float4 {cx,cy,dz,op}, float4 {r,g,b,0})
// cxy     [4096*2]@ 53248     (float2 {cx,cy} in sorted order, for fast cull)

__global__ void proj_kernel(const float* __restrict__ pos,
                            const float* __restrict__ quat,
                            const float* __restrict__ cam,
                            const float* __restrict__ K,
                            float* __restrict__ cx, float* __restrict__ cy,
                            float* __restrict__ dz, float* __restrict__ key,
                            int* __restrict__ rank) {
    int i = blockIdx.x * blockDim.x + threadIdx.x;
    if (i >= N_GAUSS) return;
    float qw = quat[0], qx = quat[1], qy = quat[2], qz = quat[3];
    float qn = 1.0f / sqrtf(qw * qw + qx * qx + qy * qy + qz * qz);
    qw *= qn; qx *= qn; qy *= qn; qz *= qn;
    float r00 = 1.f - 2.f * (qy * qy + qz * qz), r01 = 2.f * (qx * qy - qw * qz), r02 = 2.f * (qx * qz + qw * qy);
    float r10 = 2.f * (qx * qy + qw * qz), r11 = 1.f - 2.f * (qx * qx + qz * qz), r12 = 2.f * (qy * qz - qw * qx);
    float r20 = 2.f * (qx * qz - qw * qy), r21 = 2.f * (qy * qz + qw * qx), r22 = 1.f - 2.f * (qx * qx + qy * qy);
    float px = pos[3 * i] - cam[0], py = pos[3 * i + 1] - cam[1], pz = pos[3 * i + 2] - cam[2];
    float X = r00 * px + r01 * py + r02 * pz;
    float Y = r10 * px + r11 * py + r12 * pz;
    float Z = r20 * px + r21 * py + r22 * pz;
    float u = K[0] * X + K[1] * Y + K[2] * Z;
    float v = K[3] * X + K[4] * Y + K[5] * Z;
    float w = K[6] * X + K[7] * Y + K[8] * Z;
    cx[i] = u / w;
    cy[i] = v / w;
    dz[i] = Z;
    key[i] = -w;
    rank[i] = 0;          // zero-init for rank_partial's atomics (re-poison safe)
}

// Partial rank: grid (16 i-segments, 16 j-segments), 256 threads.
__global__ __launch_bounds__(256) void rank_partial_kernel(
        const float* __restrict__ keyg, int* __restrict__ rank) {
    __shared__ __align__(16) float sk[256];
    int t = threadIdx.x;
    int jbase = blockIdx.y * 256;
    sk[t] = keyg[jbase + t];
    __syncthreads();
    int i = blockIdx.x * 256 + t;
    float ki = keyg[i];
    int r = 0;
    #pragma unroll
    for (int j = 0; j < 256; j += 4) {
        float4 k4 = *reinterpret_cast<const float4*>(&sk[j]);   // LDS broadcast
        r += (k4.x < ki) || (k4.x == ki && (jbase + j + 0) < i);
        r += (k4.y < ki) || (k4.y == ki && (jbase + j + 1) < i);
        r += (k4.z < ki) || (k4.z == ki && (jbase + j + 2) < i);
        r += (k4.w < ki) || (k4.w == ki && (jbase + j + 3) < i);
    }
    if (r) atomicAdd(&rank[i], r);
}

// Scatter the sorted AoS + the compact float2 center array.
__global__ __launch_bounds__(256) void scatter_kernel(
        const int* __restrict__ rank, const float* __restrict__ cx,
        const float* __restrict__ cy, const float* __restrict__ dz,
        const float* __restrict__ colors, const float* __restrict__ opac,
        float4* __restrict__ out, float2* __restrict__ cxy) {
    int i = blockIdx.x * 256 + threadIdx.x;
    int r = rank[i];
    float x = cx[i], y = cy[i];
    out[2 * r]     = make_float4(x, y, dz[i], opac[i]);
    out[2 * r + 1] = make_float4(colors[3 * i], colors[3 * i + 1], colors[3 * i + 2], 0.f);
    cxy[r] = make_float2(x, y);
}

#define CULL2 1444.0f   // r=38 from tile center: min pixel dist 26 -> skipped alpha <= 6.7e-7
#define NSUB 64         // 64 sub-chunks of 64 Gaussians
#define CAP 512         // survivors composited per round (LDS cap)

__global__ __launch_bounds__(256) void render_kernel(
        const float4* __restrict__ gs, const float2* __restrict__ cxy,
        const float* __restrict__ bg, float* __restrict__ out) {
    __shared__ unsigned long long smask[NSUB];
    __shared__ int sprefix[NSUB + 1];
    __shared__ unsigned short sidx[N_GAUSS];          // 8 KB worst case
    __shared__ __align__(16) float4 cmp[2 * CAP];     // 16 KB
    __shared__ int swalive[4];

    int tid = threadIdx.x;
    int lane = tid & 63, wid = tid >> 6;
    // swizzle tile mapping so each CU's blocks get mixed central/edge tiles
    int tile = (blockIdx.x * 341) & 1023;             // odd multiplier: bijection mod 1024
    int tx0 = (tile & 31) * 16, ty0 = (tile >> 5) * 16;
    int j = tx0 + (tid & 15);
    int i = ty0 + (tid >> 4);
    float px = (float)j, py = (float)i;
    float tcx = tx0 + 7.5f, tcy = ty0 + 7.5f;

    // Phase A: cull (one wave per sub-chunk, 16 sub-chunks per wave, no barriers)
    for (int k = 0; k < 16; ++k) {
        int sc = k * 4 + wid;
        int g = sc * 64 + lane;
        float2 c2 = cxy[g];                           // coalesced 8B
        float ddx = c2.x - tcx, ddy = c2.y - tcy;
        bool pred = (ddx * ddx + ddy * ddy <= CULL2);
        unsigned long long m = __ballot(pred ? 1 : 0);
        if (pred) {
            int pos = __popcll(m & ((1ull << lane) - 1ull));
            sidx[sc * 64 + pos] = (unsigned short)g;
        }
        if (lane == 0) smask[sc] = m;
    }
    __syncthreads();

    // Phase B: exclusive prefix over 64 sub-chunk counts (wave 0, shfl scan)
    if (wid == 0) {
        int c = __popcll(smask[lane]);
        int inc = c;
        #pragma unroll
        for (int d = 1; d < 64; d <<= 1) {
            int n = __shfl_up(inc, d, 64);
            if (lane >= d) inc += n;
        }
        sprefix[lane] = inc - c;
        if (lane == 63) sprefix[64] = inc;            // total
    }
    __syncthreads();
    int total = sprefix[64];

    float T = 1.f;
    float cr = bg[0], cg = bg[1], cb = bg[2];
    float da = 0.f, aa = 0.f;
    bool saturated = false;

    for (int base = 0; base < total && !saturated; base += CAP) {
        int cnt = min(CAP, total - base);
        // Phase C: cooperative gather of survivor records into LDS (ordered)
        for (int s = tid; s < cnt; s += 256) {
            int gpos = base + s;
            int lo = 0, hi = NSUB;                    // invariant: pre[lo] <= gpos < pre[hi]
            #pragma unroll
            for (int it = 0; it < 6; ++it) {
                int mid = (lo + hi) >> 1;
                if (sprefix[mid] <= gpos) lo = mid; else hi = mid;
            }
            int idx = sidx[lo * 64 + (gpos - sprefix[lo])];
            cmp[2 * s]     = gs[2 * idx];
            cmp[2 * s + 1] = gs[2 * idx + 1];
        }
        __syncthreads();
        // Phase D: composite (LDS broadcast reads, no barriers except sat-check)
        for (int g = 0; g < cnt; ++g) {
            float4 GA = cmp[2 * g];
            float dx = px - GA.x, dy = py - GA.y;
            float al = __expf(-0.02f * (dx * dx + dy * dy)) * GA.w;  // op<=0.5 -> clip no-op
            float ta = T * al;
            float4 GC = cmp[2 * g + 1];
            cr += ta * GC.x; cg += ta * GC.y; cb += ta * GC.z;
            da += ta * GA.z; aa += ta;
            T -= ta;
            if ((g & 127) == 127 && g + 1 < cnt) {    // block-wide saturation check
                unsigned long long alive = __ballot(T >= 1e-6f ? 1 : 0);
                if (lane == 0) swalive[wid] = (alive != 0ull);
                __syncthreads();
                bool allsat = !(swalive[0] | swalive[1] | swalive[2] | swalive[3]);
                __syncthreads();
                if (allsat) { saturated = true; break; }
            }
        }
        __syncthreads();                               // protect cmp reuse
    }

    int pid = i * W + j;
    out[pid]          = cr;
    out[HW + pid]     = cg;
    out[2 * HW + pid] = cb;
    out[3 * HW + pid] = da;
    out[4 * HW + pid] = aa;
}

extern "C" void kernel_launch(void* const* d_in, const int* in_sizes, int n_in,
                              void* d_out, int out_size, void* d_ws, size_t ws_size,
                              hipStream_t stream) {
    const float* positions = (const float*)d_in[0];
    const float* colors    = (const float*)d_in[1];
    const float* opacities = (const float*)d_in[2];
    const float* quat      = (const float*)d_in[3];
    const float* cam       = (const float*)d_in[4];
    const float* intr      = (const float*)d_in[5];
    const float* bg        = (const float*)d_in[6];
    float* out = (float*)d_out;

    float* ws  = (float*)d_ws;
    float* cx  = ws;
    float* cy  = ws + 4096;
    float* dz  = ws + 8192;
    float* key = ws + 12288;
    int*   rank = (int*)(ws + 16384);
    float4* sorted = (float4*)(ws + 20480);
    float2* cxy    = (float2*)(ws + 53248);

    proj_kernel<<<dim3(N_GAUSS / 256), dim3(256), 0, stream>>>(
        positions, quat, cam, intr, cx, cy, dz, key, rank);
    rank_partial_kernel<<<dim3(16, 16), dim3(256), 0, stream>>>(key, rank);
    scatter_kernel<<<dim3(N_GAUSS / 256), dim3(256), 0, stream>>>(
        rank, cx, cy, dz, colors, opacities, sorted, cxy);
    render_kernel<<<dim3(W / 16 * H / 16), dim3(256), 0, stream>>>(
        sorted, cxy, bg, out);
}

// Round 7
// 118.336 us; speedup vs baseline: 1.0724x; 1.0724x over previous
//
#include <hip/hip_runtime.h>
#include <hip/hip_bf16.h>

#define N_GAUSS 4096
#define H 512
#define W 512
#define HW (H * W)

// ---------------- workspace layout (floats) ----------------
// cx      [4096]   @ 0
// cy      [4096]   @ 4096
// dz      [4096]   @ 8192
// key     [4096]   @ 12288
// rank    [4096]   @ 16384    (int, zeroed by proj_kernel)
// sorted  [4096*8] @ 20480    (AoS: float4 {cx,cy,dz,op}, float4 {r,g,b,0})
// cxy     [4096*2] @ 53248    (float2 {cx,cy} in sorted order)
// segbuf  [4*6*HW] @ 65536    (per-segment {r,g,b,d,a,T}[HW])

#define SEG 4
#define GSEG (N_GAUSS / SEG)   // 1024 Gaussians per segment
#define NSUB (GSEG / 64)       // 16 sub-chunks of 64

__global__ void proj_kernel(const float* __restrict__ pos,
                            const float* __restrict__ quat,
                            const float* __restrict__ cam,
                            const float* __restrict__ K,
                            float* __restrict__ cx, float* __restrict__ cy,
                            float* __restrict__ dz, float* __restrict__ key,
                            int* __restrict__ rank) {
    int i = blockIdx.x * blockDim.x + threadIdx.x;
    if (i >= N_GAUSS) return;
    float qw = quat[0], qx = quat[1], qy = quat[2], qz = quat[3];
    float qn = 1.0f / sqrtf(qw * qw + qx * qx + qy * qy + qz * qz);
    qw *= qn; qx *= qn; qy *= qn; qz *= qn;
    float r00 = 1.f - 2.f * (qy * qy + qz * qz), r01 = 2.f * (qx * qy - qw * qz), r02 = 2.f * (qx * qz + qw * qy);
    float r10 = 2.f * (qx * qy + qw * qz), r11 = 1.f - 2.f * (qx * qx + qz * qz), r12 = 2.f * (qy * qz - qw * qx);
    float r20 = 2.f * (qx * qz - qw * qy), r21 = 2.f * (qy * qz + qw * qx), r22 = 1.f - 2.f * (qx * qx + qy * qy);
    float px = pos[3 * i] - cam[0], py = pos[3 * i + 1] - cam[1], pz = pos[3 * i + 2] - cam[2];
    float X = r00 * px + r01 * py + r02 * pz;
    float Y = r10 * px + r11 * py + r12 * pz;
    float Z = r20 * px + r21 * py + r22 * pz;
    float u = K[0] * X + K[1] * Y + K[2] * Z;
    float v = K[3] * X + K[4] * Y + K[5] * Z;
    float w = K[6] * X + K[7] * Y + K[8] * Z;
    cx[i] = u / w;
    cy[i] = v / w;
    dz[i] = Z;
    key[i] = -w;
    rank[i] = 0;          // zero-init for rank_partial's atomics (re-poison safe)
}

// Partial rank: grid (16 i-segments, 16 j-segments), 256 threads.
__global__ __launch_bounds__(256) void rank_partial_kernel(
        const float* __restrict__ keyg, int* __restrict__ rank) {
    __shared__ __align__(16) float sk[256];
    int t = threadIdx.x;
    int jbase = blockIdx.y * 256;
    sk[t] = keyg[jbase + t];
    __syncthreads();
    int i = blockIdx.x * 256 + t;
    float ki = keyg[i];
    int r = 0;
    #pragma unroll
    for (int j = 0; j < 256; j += 4) {
        float4 k4 = *reinterpret_cast<const float4*>(&sk[j]);   // LDS broadcast
        r += (k4.x < ki) || (k4.x == ki && (jbase + j + 0) < i);
        r += (k4.y < ki) || (k4.y == ki && (jbase + j + 1) < i);
        r += (k4.z < ki) || (k4.z == ki && (jbase + j + 2) < i);
        r += (k4.w < ki) || (k4.w == ki && (jbase + j + 3) < i);
    }
    if (r) atomicAdd(&rank[i], r);
}

// Scatter the sorted AoS + compact float2 center array.
__global__ __launch_bounds__(256) void scatter_kernel(
        const int* __restrict__ rank, const float* __restrict__ cx,
        const float* __restrict__ cy, const float* __restrict__ dz,
        const float* __restrict__ colors, const float* __restrict__ opac,
        float4* __restrict__ out, float2* __restrict__ cxy) {
    int i = blockIdx.x * 256 + threadIdx.x;
    int r = rank[i];
    float x = cx[i], y = cy[i];
    out[2 * r]     = make_float4(x, y, dz[i], opac[i]);
    out[2 * r + 1] = make_float4(colors[3 * i], colors[3 * i + 1], colors[3 * i + 2], 0.f);
    cxy[r] = make_float2(x, y);
}

#define CULL2 1444.0f   // r=38 from tile center: min pixel dist 26 -> skipped alpha <= 6.7e-7
#define CAP 512

// One block per (tile, depth-segment): composite the segment's survivors into
// (C=0-based color/depth/alpha accumulators, T) — combined associatively later.
__global__ __launch_bounds__(256) void seg_render_kernel(
        const float4* __restrict__ gs, const float2* __restrict__ cxy,
        float* __restrict__ segbuf) {
    __shared__ unsigned long long smask[NSUB];
    __shared__ int sprefix[NSUB + 1];
    __shared__ unsigned short sidx[GSEG];
    __shared__ __align__(16) float4 cmp[2 * CAP];
    __shared__ int swalive[4];

    int tid = threadIdx.x;
    int lane = tid & 63, wid = tid >> 6;
    int tile = (blockIdx.x * 341) & 1023;             // odd multiplier: bijection mod 1024
    int seg = blockIdx.y;
    int gbase = seg * GSEG;
    int tx0 = (tile & 31) * 16, ty0 = (tile >> 5) * 16;
    int j = tx0 + (tid & 15);
    int i = ty0 + (tid >> 4);
    float px = (float)j, py = (float)i;
    float tcx = tx0 + 7.5f, tcy = ty0 + 7.5f;

    // Phase A: cull 1024 Gaussians (4 ballot rounds per wave, no barriers)
    for (int k = 0; k < NSUB / 4; ++k) {
        int sc = k * 4 + wid;                          // sub-chunk 0..15
        int g = gbase + sc * 64 + lane;
        float2 c2 = cxy[g];
        float ddx = c2.x - tcx, ddy = c2.y - tcy;
        bool pred = (ddx * ddx + ddy * ddy <= CULL2);
        unsigned long long m = __ballot(pred ? 1 : 0);
        if (pred) {
            int pos = __popcll(m & ((1ull << lane) - 1ull));
            sidx[sc * 64 + pos] = (unsigned short)g;
        }
        if (lane == 0) smask[sc] = m;
    }
    __syncthreads();

    // Phase B: exclusive prefix over 16 counts (wave 0 low lanes)
    if (wid == 0 && lane < NSUB) {
        int c = __popcll(smask[lane]);
        int inc = c;
        #pragma unroll
        for (int d = 1; d < NSUB; d <<= 1) {
            int n = __shfl_up(inc, d, 64);
            if (lane >= d) inc += n;
        }
        sprefix[lane] = inc - c;
        if (lane == NSUB - 1) sprefix[NSUB] = inc;
    }
    __syncthreads();
    int total = sprefix[NSUB];

    float T = 1.f, cr = 0.f, cg = 0.f, cb = 0.f, da = 0.f, aa = 0.f;
    bool saturated = false;

    for (int base = 0; base < total && !saturated; base += CAP) {
        int cnt = min(CAP, total - base);
        // Phase C: ordered gather of survivor records into LDS
        for (int s = tid; s < cnt; s += 256) {
            int gpos = base + s;
            int lo = 0, hi = NSUB;
            #pragma unroll
            for (int it = 0; it < 4; ++it) {           // log2(16)
                int mid = (lo + hi) >> 1;
                if (sprefix[mid] <= gpos) lo = mid; else hi = mid;
            }
            int idx = sidx[lo * 64 + (gpos - sprefix[lo])];
            cmp[2 * s]     = gs[2 * idx];
            cmp[2 * s + 1] = gs[2 * idx + 1];
        }
        __syncthreads();
        // Phase D: composite
        for (int g = 0; g < cnt; ++g) {
            float4 GA = cmp[2 * g];
            float dx = px - GA.x, dy = py - GA.y;
            float al = __expf(-0.02f * (dx * dx + dy * dy)) * GA.w;  // op<=0.5 -> clip no-op
            float ta = T * al;
            float4 GC = cmp[2 * g + 1];
            cr += ta * GC.x; cg += ta * GC.y; cb += ta * GC.z;
            da += ta * GA.z; aa += ta;
            T -= ta;
            if ((g & 127) == 127 && g + 1 < cnt) {     // within-segment saturation
                unsigned long long alive = __ballot(T >= 1e-6f ? 1 : 0);
                if (lane == 0) swalive[wid] = (alive != 0ull);
                __syncthreads();
                bool allsat = !(swalive[0] | swalive[1] | swalive[2] | swalive[3]);
                __syncthreads();
                if (allsat) { saturated = true; break; }
            }
        }
        __syncthreads();
    }

    int pid = i * W + j;
    float* o = segbuf + seg * 6 * HW + pid;
    o[0 * HW] = cr;  o[1 * HW] = cg;  o[2 * HW] = cb;
    o[3 * HW] = da;  o[4 * HW] = aa;  o[5 * HW] = T;
}

// Fold segments back-to-front: acc = C_s + T_s * acc; add background.
__global__ __launch_bounds__(256) void combine_kernel(
        const float* __restrict__ segbuf, const float* __restrict__ bg,
        float* __restrict__ out) {
    int pid = blockIdx.x * 256 + threadIdx.x;
    float r = 0.f, g = 0.f, b = 0.f, d = 0.f, a = 0.f;
    #pragma unroll
    for (int s = SEG - 1; s >= 0; --s) {
        const float* o = segbuf + s * 6 * HW + pid;
        float T = o[5 * HW];
        r = o[0 * HW] + T * r;
        g = o[1 * HW] + T * g;
        b = o[2 * HW] + T * b;
        d = o[3 * HW] + T * d;
        a = o[4 * HW] + T * a;
    }
    out[pid]          = bg[0] + r;
    out[HW + pid]     = bg[1] + g;
    out[2 * HW + pid] = bg[2] + b;
    out[3 * HW + pid] = d;
    out[4 * HW + pid] = a;
}

extern "C" void kernel_launch(void* const* d_in, const int* in_sizes, int n_in,
                              void* d_out, int out_size, void* d_ws, size_t ws_size,
                              hipStream_t stream) {
    const float* positions = (const float*)d_in[0];
    const float* colors    = (const float*)d_in[1];
    const float* opacities = (const float*)d_in[2];
    const float* quat      = (const float*)d_in[3];
    const float* cam       = (const float*)d_in[4];
    const float* intr      = (const float*)d_in[5];
    const float* bg        = (const float*)d_in[6];
    float* out = (float*)d_out;

    float* ws  = (float*)d_ws;
    float* cx  = ws;
    float* cy  = ws + 4096;
    float* dz  = ws + 8192;
    float* key = ws + 12288;
    int*   rank = (int*)(ws + 16384);
    float4* sorted = (float4*)(ws + 20480);
    float2* cxy    = (float2*)(ws + 53248);
    float* segbuf  = ws + 65536;

    proj_kernel<<<dim3(N_GAUSS / 256), dim3(256), 0, stream>>>(
        positions, quat, cam, intr, cx, cy, dz, key, rank);
    rank_partial_kernel<<<dim3(16, 16), dim3(256), 0, stream>>>(key, rank);
    scatter_kernel<<<dim3(N_GAUSS / 256), dim3(256), 0, stream>>>(
        rank, cx, cy, dz, colors, opacities, sorted, cxy);
    seg_render_kernel<<<dim3(1024, SEG), dim3(256), 0, stream>>>(
        sorted, cxy, segbuf);
    combine_kernel<<<dim3(HW / 256), dim3(256), 0, stream>>>(segbuf, bg, out);
}